// Round 14
// baseline (2466.696 us; speedup 1.0000x reference)
//
#include <hip/hip_runtime.h>
#include <hip/hip_bf16.h>
#include <math.h>

#define NB 128
#define NR 32
#define EPAD 40    // fA row stride in shorts
#define HPAD 136   // H/XA row stride in shorts (272B, 16B-aligned rows)

// xf layout: feature-permuted (storage col c = col*8 + nt holds feature
// nt*16+col). agg layout: ORIGINAL feature order, bf16, packed-bf16 atomics.
// r7: never permute the scatter side. r10: redundant per-lane edata loads
// regress. r12: occupancy is not LDS-limited. r14: 2-tile software pipeline
// in the edge kernel — tile1 meta/gather/fA latencies hidden under tile0
// compute; fA/H buffers reused, meta double-buffered.

static constexpr float CUTOFF_F    = 10.0f;
static constexpr float RBF_STEP    = 10.0f / 31.0f;
static constexpr float RBF_COEFF   = -4.805f;           // -0.5/(10/31)^2
static constexpr float LOG2_F      = 0.69314718055994531f;
static constexpr float PI_OVER_CUT = 0.314159265358979f;

typedef __attribute__((ext_vector_type(8))) short bf16x8;
typedef __attribute__((ext_vector_type(2))) short bf16x2;
typedef __attribute__((ext_vector_type(4))) float f32x4;

__device__ __forceinline__ short f2bs(float x) {
    __hip_bfloat16 h = __float2bfloat16(x);   // RNE
    return *reinterpret_cast<short*>(&h);
}
__device__ __forceinline__ float bs2f(unsigned short u) {
    unsigned int v = ((unsigned int)u) << 16;
    return __uint_as_float(v);
}
__device__ __forceinline__ float ssp_f(float v) {
    return fmaxf(v, 0.0f) + __logf(1.0f + __expf(-fabsf(v))) - LOG2_F;
}
__device__ __forceinline__ float silu_f(float v) {
    return v / (1.0f + __expf(-v));
}

// packed bf16 atomic add (2 features per op)
__device__ __forceinline__ void atomic_pk_add_bf16(short* addr, float lo, float hi) {
#if __has_builtin(__builtin_amdgcn_global_atomic_fadd_v2bf16)
    typedef bf16x2 __attribute__((address_space(1))) *gptr;
    bf16x2 v;
    v[0] = f2bs(lo);
    v[1] = f2bs(hi);
    __builtin_amdgcn_global_atomic_fadd_v2bf16((gptr)(unsigned long long)addr, v);
#else
    unsigned int* w = (unsigned int*)addr;
    unsigned int old = *w, assumed;
    do {
        assumed = old;
        float fl = bs2f((unsigned short)(assumed & 0xffff)) + lo;
        float fh = bs2f((unsigned short)(assumed >> 16)) + hi;
        unsigned int nv = ((unsigned int)(unsigned short)f2bs(fh) << 16) |
                          (unsigned short)f2bs(fl);
        old = atomicCAS(w, assumed, nv);
    } while (old != assumed);
#endif
}

// flush one merged run: 8 accumulated features/lane -> 4 pk atomics/lane.
__device__ __forceinline__ void flush_pk(short* aggrow, const float* accum, int col) {
    bool even = ((col & 1) == 0);
#pragma unroll
    for (int q = 0; q < 4; q++) {
        float a = accum[2 * q], b = accum[2 * q + 1];
        float pa = __shfl_xor(a, 1);
        float pb = __shfl_xor(b, 1);
        int nbase = even ? (2 * q) * 16 + col : (2 * q + 1) * 16 + (col - 1);
        float lo = even ? a : pb;
        float hi = even ? pa : b;
        atomic_pk_add_bf16(aggrow + nbase, lo, hi);
    }
}

// ---------------------------------------------------------------------------
// Weight prep: dst[b][c][r] = bf16(src[b][r][c])
// ---------------------------------------------------------------------------
__global__ void transpose_cvt(const float* __restrict__ src, short* __restrict__ dst,
                              int R, int C, int total) {
    int t = blockIdx.x * blockDim.x + threadIdx.x;
    if (t >= total) return;
    int rc = R * C;
    int b = t / rc;
    int rem = t - b * rc;
    int c = rem / R;
    int r = rem - c * R;
    dst[t] = f2bs(src[(size_t)b * rc + (size_t)r * C + c]);
}

// ---------------------------------------------------------------------------
// Edge prep: distances + per-atom histogram. 4 edges/thread for MLP.
// ---------------------------------------------------------------------------
__global__ void edge_prep4(const float* __restrict__ pos,
                           const int* __restrict__ idx_i,
                           const int* __restrict__ idx_j,
                           float* __restrict__ d_ij,
                           int* __restrict__ hist,
                           int E) {
    int b0 = blockIdx.x * 1024 + threadIdx.x;
    int ia[4], ib[4];
    bool val[4];
#pragma unroll
    for (int k = 0; k < 4; k++) {
        int e = b0 + k * 256;
        val[k] = (e < E);
        ia[k] = val[k] ? idx_i[e] : 0;
        ib[k] = val[k] ? idx_j[e] : 0;
    }
    float ax[4], ay[4], az[4], bx[4], by[4], bz[4];
#pragma unroll
    for (int k = 0; k < 4; k++) {
        const float* pa = pos + ia[k] * 3;
        ax[k] = pa[0]; ay[k] = pa[1]; az[k] = pa[2];
    }
#pragma unroll
    for (int k = 0; k < 4; k++) {
        const float* pb = pos + ib[k] * 3;
        bx[k] = pb[0]; by[k] = pb[1]; bz[k] = pb[2];
    }
#pragma unroll
    for (int k = 0; k < 4; k++) {
        if (!val[k]) continue;
        float dx = ax[k] - bx[k], dy = ay[k] - by[k], dz = az[k] - bz[k];
        float d = sqrtf(dx * dx + dy * dy + dz * dz);
        d_ij[b0 + k * 256] = d;
        if (d < CUTOFF_F) atomicAdd(&hist[ia[k]], 1);
    }
}

// ---------------------------------------------------------------------------
// Single-block exclusive scan of hist[N] -> cursor[N]  (1024 threads).
// ---------------------------------------------------------------------------
__global__ __launch_bounds__(1024) void scan_hist(const int* __restrict__ hist,
                                                  int* __restrict__ cursor, int N) {
    __shared__ int part[1024];
    int t = threadIdx.x;
    int chunk = (N + 1023) / 1024;
    int lo = t * chunk;
    int hi = min(lo + chunk, N);
    int s = 0;
    for (int i = lo; i < hi; i++) s += hist[i];
    part[t] = s;
    __syncthreads();
    for (int d = 1; d < 1024; d <<= 1) {
        int v = (t >= d) ? part[t - d] : 0;
        __syncthreads();
        part[t] += v;
        __syncthreads();
    }
    int run = (t == 0) ? 0 : part[t - 1];
    for (int i = lo; i < hi; i++) {
        cursor[i] = run;
        run += hist[i];
    }
}

// ---------------------------------------------------------------------------
// Scatter active edges into idx_i-grouped order. 4 edges/thread for MLP.
// ---------------------------------------------------------------------------
__global__ void scatter_sorted4(const float* __restrict__ d_ij,
                                const int* __restrict__ idx_i,
                                const int* __restrict__ idx_j,
                                const int* __restrict__ edge_attr,
                                int* __restrict__ cursor,
                                float4* __restrict__ edata,
                                int* __restrict__ sIarr, int E) {
    int b0 = blockIdx.x * 1024 + threadIdx.x;
    float d[4]; int ii[4], jj[4], at[4]; bool act[4];
#pragma unroll
    for (int k = 0; k < 4; k++) {
        int e = b0 + k * 256;
        bool v = (e < E);
        d[k] = v ? d_ij[e] : 1e9f;
        act[k] = (d[k] < CUTOFF_F);
        ii[k] = act[k] ? idx_i[e] : 0;
        jj[k] = act[k] ? idx_j[e] : 0;
        at[k] = act[k] ? edge_attr[e] : 0;
    }
    int p[4];
#pragma unroll
    for (int k = 0; k < 4; k++)
        if (act[k]) p[k] = atomicAdd(&cursor[ii[k]], 1);
#pragma unroll
    for (int k = 0; k < 4; k++) {
        if (!act[k]) continue;
        float4 v;
        v.x = d[k];
        v.y = 0.5f * (__cosf(d[k] * PI_OVER_CUT) + 1.0f);
        v.z = __int_as_float(jj[k]);
        v.w = __int_as_float(at[k]);
        edata[p[k]] = v;
        sIarr[p[k]] = ii[k];
    }
}

// ---------------------------------------------------------------------------
// x = ele_emb[z] + res_emb[z_res]
// ---------------------------------------------------------------------------
__global__ void atom_embed(const int* __restrict__ z,
                           const int* __restrict__ z_res,
                           const float* __restrict__ ele_emb,
                           const float* __restrict__ res_emb,
                           float* __restrict__ x, int N) {
    int t = blockIdx.x * blockDim.x + threadIdx.x;
    if (t >= N * NB) return;
    int n = t >> 7, c = t & 127;
    x[t] = ele_emb[z[n] * NB + c] + res_emb[z_res[n] * NB + c];
}

// ---------------------------------------------------------------------------
// xf(bf16, permuted cols) = in(fp32) @ W  via MFMA. First-iteration in2f.
// ---------------------------------------------------------------------------
__global__ __launch_bounds__(256, 4) void node_in2f_mfma(
    const float* __restrict__ x, const short* __restrict__ WT,
    short* __restrict__ xf, int N) {
    __shared__ __align__(16) short XA[64 * HPAD];
    int a0 = blockIdx.x * 64;
    int t = threadIdx.x;
#pragma unroll
    for (int c = 0; c < 4; c++) {
        int chunk = t + c * 256;
        int row = chunk >> 4;
        int col = (chunk & 15) * 8;
        short v[8];
        if (a0 + row < N) {
            const float* src = x + (size_t)(a0 + row) * NB + col;
            float4 f0 = *(const float4*)src;
            float4 f1 = *(const float4*)(src + 4);
            v[0] = f2bs(f0.x); v[1] = f2bs(f0.y); v[2] = f2bs(f0.z); v[3] = f2bs(f0.w);
            v[4] = f2bs(f1.x); v[5] = f2bs(f1.y); v[6] = f2bs(f1.z); v[7] = f2bs(f1.w);
        } else {
#pragma unroll
            for (int j = 0; j < 8; j++) v[j] = 0;
        }
        *(bf16x8*)&XA[row * HPAD + col] = *(bf16x8*)v;
    }
    __syncthreads();

    int wid = t >> 6, lane = t & 63;
    int quad = lane >> 4, col = lane & 15;
    int mrow = wid * 16 + col;

    f32x4 acc[8] = {};
#pragma unroll
    for (int kt = 0; kt < 4; kt++) {
        bf16x8 a = *(bf16x8*)&XA[mrow * HPAD + kt * 32 + quad * 8];
#pragma unroll
        for (int nt = 0; nt < 8; nt++) {
            bf16x8 b = *(const bf16x8*)&WT[(nt * 16 + col) * NB + kt * 32 + quad * 8];
            acc[nt] = __builtin_amdgcn_mfma_f32_16x16x32_bf16(a, b, acc[nt], 0, 0, 0);
        }
    }
#pragma unroll
    for (int nt = 0; nt < 8; nt++) {
        int cst = col * 8 + nt;   // permuted storage col
#pragma unroll
        for (int r = 0; r < 4; r++) {
            int m = wid * 16 + quad * 4 + r;
            if (a0 + m < N) xf[(size_t)(a0 + m) * NB + cst] = f2bs(acc[nt][r]);
        }
    }
}

// ---------------------------------------------------------------------------
// Fused: v = ssp(agg@W1+b1)@W2+b2 ; x += v ; xf_next(bf16, permuted) = x @ Wn
// agg bf16 original order; re-zeroed here for the next iteration.
// ---------------------------------------------------------------------------
__global__ __launch_bounds__(256, 4) void node_fused_mfma(
    short* __restrict__ agg,
    const short* __restrict__ W1T, const float* __restrict__ b1,
    const short* __restrict__ W2T, const float* __restrict__ b2,
    const short* __restrict__ WnT,
    float* __restrict__ x, short* __restrict__ xf, int N) {
    __shared__ __align__(16) short XA[64 * HPAD];
    __shared__ __align__(16) short H[64 * HPAD];
    int a0 = blockIdx.x * 64;
    int t = threadIdx.x;
#pragma unroll
    for (int c = 0; c < 4; c++) {
        int chunk = t + c * 256;
        int row = chunk >> 4;
        int col = (chunk & 15) * 8;
        bf16x8 v = {0, 0, 0, 0, 0, 0, 0, 0};
        if (a0 + row < N) {
            short* src = agg + (size_t)(a0 + row) * NB + col;
            v = *(const bf16x8*)src;
            *(bf16x8*)src = (bf16x8){0, 0, 0, 0, 0, 0, 0, 0};  // re-zero for next iter
        }
        *(bf16x8*)&XA[row * HPAD + col] = v;
    }
    __syncthreads();

    int wid = t >> 6, lane = t & 63;
    int quad = lane >> 4, col = lane & 15;
    int mrow = wid * 16 + col;

    // GEMM1 + ssp -> H
    {
        f32x4 acc[8] = {};
#pragma unroll
        for (int kt = 0; kt < 4; kt++) {
            bf16x8 a = *(bf16x8*)&XA[mrow * HPAD + kt * 32 + quad * 8];
#pragma unroll
            for (int nt = 0; nt < 8; nt++) {
                bf16x8 b = *(const bf16x8*)&W1T[(nt * 16 + col) * NB + kt * 32 + quad * 8];
                acc[nt] = __builtin_amdgcn_mfma_f32_16x16x32_bf16(a, b, acc[nt], 0, 0, 0);
            }
        }
#pragma unroll
        for (int nt = 0; nt < 8; nt++) {
            int n = nt * 16 + col;
            float bias = b1[n];
#pragma unroll
            for (int r = 0; r < 4; r++) {
                int m = wid * 16 + quad * 4 + r;
                H[m * HPAD + n] = f2bs(ssp_f(acc[nt][r] + bias));
            }
        }
    }
    __syncthreads();

    // GEMM2 + residual: x_new -> global fp32 + XA bf16 (reuse)
    {
        f32x4 acc[8] = {};
#pragma unroll
        for (int kt = 0; kt < 4; kt++) {
            bf16x8 a = *(bf16x8*)&H[mrow * HPAD + kt * 32 + quad * 8];
#pragma unroll
            for (int nt = 0; nt < 8; nt++) {
                bf16x8 b = *(const bf16x8*)&W2T[(nt * 16 + col) * NB + kt * 32 + quad * 8];
                acc[nt] = __builtin_amdgcn_mfma_f32_16x16x32_bf16(a, b, acc[nt], 0, 0, 0);
            }
        }
#pragma unroll
        for (int nt = 0; nt < 8; nt++) {
            int n = nt * 16 + col;
            float bias = b2[n];
#pragma unroll
            for (int r = 0; r < 4; r++) {
                int m = wid * 16 + quad * 4 + r;
                float xn = 0.0f;
                if (a0 + m < N) {
                    size_t o = (size_t)(a0 + m) * NB + n;
                    xn = x[o] + acc[nt][r] + bias;
                    x[o] = xn;
                }
                XA[m * HPAD + n] = f2bs(xn);
            }
        }
    }
    __syncthreads();

    // GEMM3: xf = x_new @ Wn  (bf16 out, permuted storage cols)
    {
        f32x4 acc[8] = {};
#pragma unroll
        for (int kt = 0; kt < 4; kt++) {
            bf16x8 a = *(bf16x8*)&XA[mrow * HPAD + kt * 32 + quad * 8];
#pragma unroll
            for (int nt = 0; nt < 8; nt++) {
                bf16x8 b = *(const bf16x8*)&WnT[(nt * 16 + col) * NB + kt * 32 + quad * 8];
                acc[nt] = __builtin_amdgcn_mfma_f32_16x16x32_bf16(a, b, acc[nt], 0, 0, 0);
            }
        }
#pragma unroll
        for (int nt = 0; nt < 8; nt++) {
            int cst = col * 8 + nt;
#pragma unroll
            for (int r = 0; r < 4; r++) {
                int m = wid * 16 + quad * 4 + r;
                if (a0 + m < N) xf[(size_t)(a0 + m) * NB + cst] = f2bs(acc[nt][r]);
            }
        }
    }
}

// ---------------------------------------------------------------------------
// Last iteration fused with head.
// ---------------------------------------------------------------------------
__global__ __launch_bounds__(256, 4) void node_out_head_mfma(
    const short* __restrict__ agg,
    const short* __restrict__ W1T, const float* __restrict__ b1,
    const short* __restrict__ W2T, const float* __restrict__ b2,
    const float* __restrict__ x, const int* __restrict__ batch,
    const short* __restrict__ hW1T, const float* __restrict__ hb1,
    const float* __restrict__ hW2,
    float* __restrict__ out, int N) {
    __shared__ __align__(16) short XA[64 * HPAD];
    __shared__ __align__(16) short H[64 * HPAD];
    __shared__ int sbat[64];
    __shared__ float rowval[64];
    int a0 = blockIdx.x * 64;
    int t = threadIdx.x;

    if (t < 64) sbat[t] = (a0 + t < N) ? batch[a0 + t] : -1;
#pragma unroll
    for (int c = 0; c < 4; c++) {
        int chunk = t + c * 256;
        int row = chunk >> 4;
        int col = (chunk & 15) * 8;
        bf16x8 v = {0, 0, 0, 0, 0, 0, 0, 0};
        if (a0 + row < N) v = *(const bf16x8*)&agg[(size_t)(a0 + row) * NB + col];
        *(bf16x8*)&XA[row * HPAD + col] = v;
    }
    __syncthreads();

    int wid = t >> 6, lane = t & 63;
    int quad = lane >> 4, col = lane & 15;
    int mrow = wid * 16 + col;

    // GEMM1 + ssp -> H
    {
        f32x4 acc[8] = {};
#pragma unroll
        for (int kt = 0; kt < 4; kt++) {
            bf16x8 a = *(bf16x8*)&XA[mrow * HPAD + kt * 32 + quad * 8];
#pragma unroll
            for (int nt = 0; nt < 8; nt++) {
                bf16x8 b = *(const bf16x8*)&W1T[(nt * 16 + col) * NB + kt * 32 + quad * 8];
                acc[nt] = __builtin_amdgcn_mfma_f32_16x16x32_bf16(a, b, acc[nt], 0, 0, 0);
            }
        }
#pragma unroll
        for (int nt = 0; nt < 8; nt++) {
            int n = nt * 16 + col;
            float bias = b1[n];
#pragma unroll
            for (int r = 0; r < 4; r++) {
                int m = wid * 16 + quad * 4 + r;
                H[m * HPAD + n] = f2bs(ssp_f(acc[nt][r] + bias));
            }
        }
    }
    __syncthreads();

    // GEMM2 + residual in registers; row sums of squares via 16-lane shuffle
    float xnv[8][4];
    float ssq[4] = {0.f, 0.f, 0.f, 0.f};
    {
        f32x4 acc[8] = {};
#pragma unroll
        for (int kt = 0; kt < 4; kt++) {
            bf16x8 a = *(bf16x8*)&H[mrow * HPAD + kt * 32 + quad * 8];
#pragma unroll
            for (int nt = 0; nt < 8; nt++) {
                bf16x8 b = *(const bf16x8*)&W2T[(nt * 16 + col) * NB + kt * 32 + quad * 8];
                acc[nt] = __builtin_amdgcn_mfma_f32_16x16x32_bf16(a, b, acc[nt], 0, 0, 0);
            }
        }
#pragma unroll
        for (int nt = 0; nt < 8; nt++) {
            int n = nt * 16 + col;
            float bias = b2[n];
#pragma unroll
            for (int r = 0; r < 4; r++) {
                int m = wid * 16 + quad * 4 + r;
                float xn = 0.0f;
                if (a0 + m < N) xn = x[(size_t)(a0 + m) * NB + n] + acc[nt][r] + bias;
                xnv[nt][r] = xn;
                ssq[r] += xn * xn;
            }
        }
    }
#pragma unroll
    for (int r = 0; r < 4; r++) {
#pragma unroll
        for (int m = 1; m < 16; m <<= 1) ssq[r] += __shfl_xor(ssq[r], m);
    }
    float inv[4];
#pragma unroll
    for (int r = 0; r < 4; r++) inv[r] = 1.0f / fmaxf(sqrtf(ssq[r]), 1e-12f);
    __syncthreads();
#pragma unroll
    for (int nt = 0; nt < 8; nt++) {
        int n = nt * 16 + col;
#pragma unroll
        for (int r = 0; r < 4; r++) {
            int m = wid * 16 + quad * 4 + r;
            XA[m * HPAD + n] = f2bs(silu_f(xnv[nt][r] * inv[r]));
        }
    }
    __syncthreads();

    // head GEMM
    f32x4 acc[8] = {};
#pragma unroll
    for (int kt = 0; kt < 4; kt++) {
        bf16x8 a = *(bf16x8*)&XA[mrow * HPAD + kt * 32 + quad * 8];
#pragma unroll
        for (int nt = 0; nt < 8; nt++) {
            bf16x8 b = *(const bf16x8*)&hW1T[(nt * 16 + col) * NB + kt * 32 + quad * 8];
            acc[nt] = __builtin_amdgcn_mfma_f32_16x16x32_bf16(a, b, acc[nt], 0, 0, 0);
        }
    }
    float partial[4] = {0.f, 0.f, 0.f, 0.f};
#pragma unroll
    for (int nt = 0; nt < 8; nt++) {
        int n = nt * 16 + col;
        float bias = hb1[n];
        float w2 = hW2[n];
#pragma unroll
        for (int r = 0; r < 4; r++) partial[r] += silu_f(acc[nt][r] + bias) * w2;
    }
#pragma unroll
    for (int r = 0; r < 4; r++) {
#pragma unroll
        for (int d = 1; d < 16; d <<= 1) partial[r] += __shfl_xor(partial[r], d);
    }
    if (col == 0) {
#pragma unroll
        for (int r = 0; r < 4; r++) rowval[wid * 16 + quad * 4 + r] = partial[r];
    }
    __syncthreads();

    if (t < 64) {
        int b = sbat[t];
        bool headf = (b >= 0) && (t == 0 || sbat[t - 1] != b);
        if (headf) {
            float s = 0.0f;
            int rr = t;
            while (rr < 64 && sbat[rr] == b) { s += rowval[rr]; rr++; }
            atomicAdd(&out[b], s);
        }
    }
}

// ---------------------------------------------------------------------------
// r14 edge kernel: 2 tiles (128 sorted edges) per block, software-pipelined.
// Tile1's meta staged during tile0's fA phase; tile1's gather issued during
// tile0's GEMM1; tile1's fA computed during tile0's GEMM2+epilogue.
// fA/H buffers reused across tiles; meta double-buffered.
// ---------------------------------------------------------------------------
__global__ __launch_bounds__(256, 4) void edge_fused_mfma2(
    const float4* __restrict__ edata, const int* __restrict__ sIarr,
    const int* __restrict__ rowend, int natoms,
    const float* __restrict__ edge_emb,
    const short* __restrict__ W1T, const float* __restrict__ b1,
    const short* __restrict__ W2T, const float* __restrict__ b2,
    const short* __restrict__ xf, short* __restrict__ agg) {
    __shared__ __align__(16) short fA[64 * EPAD];
    __shared__ __align__(16) short H[64 * HPAD];
    __shared__ float sD[2][64], sRC[2][64];
    __shared__ int sI[2][64], sJ[2][64], sA[2][64];

    int cnt = rowend[natoms - 1];
    int base0 = blockIdx.x * 128;
    if (base0 >= cnt) return;
    int base1 = base0 + 64;
    int t = threadIdx.x;

    int wid = t >> 6, lane = t & 63;
    int quad = lane >> 4, col = lane & 15;
    int mrow = wid * 16 + col;
    int e0 = wid * 16 + quad * 4;
    const unsigned short* xg = (const unsigned short*)xf;

    float b2v[8];
#pragma unroll
    for (int nt = 0; nt < 8; nt++) b2v[nt] = b2[nt * 16 + col];

    // --- stage meta0 ---
    if (t < 64) {
        int ei = base0 + t;
        if (ei < cnt) {
            float4 v = edata[ei];
            sD[0][t] = v.x; sRC[0][t] = v.y;
            sJ[0][t] = __float_as_int(v.z);
            sA[0][t] = __float_as_int(v.w);
            sI[0][t] = sIarr[ei];
        } else {
            sD[0][t] = 1e9f; sRC[0][t] = 0.0f; sJ[0][t] = 0; sA[0][t] = 0; sI[0][t] = 0;
        }
    }
    __syncthreads();

    // --- phase A: gather xv0, fA(tile0), stage meta1 ---
    bf16x8 xv0[4];
#pragma unroll
    for (int r = 0; r < 4; r++)
        xv0[r] = *(const bf16x8*)&xg[(size_t)sJ[0][e0 + r] * NB + col * 8];
    {
        int e_loc = t >> 2;
        int r0 = (t & 3) * 8;
        short v[8];
        if (base0 + e_loc < cnt) {
            float d = sD[0][e_loc];
            const float* em = edge_emb + sA[0][e_loc] * NR + r0;
#pragma unroll
            for (int j = 0; j < 8; j++) {
                float off = (float)(r0 + j) * RBF_STEP;
                float dd = d - off;
                v[j] = f2bs(__expf(RBF_COEFF * dd * dd) + em[j]);
            }
        } else {
#pragma unroll
            for (int j = 0; j < 8; j++) v[j] = 0;
        }
        *(bf16x8*)&fA[e_loc * EPAD + r0] = *(bf16x8*)v;
    }
    if (t < 64) {
        int ei = base1 + t;
        if (ei < cnt) {
            float4 v = edata[ei];
            sD[1][t] = v.x; sRC[1][t] = v.y;
            sJ[1][t] = __float_as_int(v.z);
            sA[1][t] = __float_as_int(v.w);
            sI[1][t] = sIarr[ei];
        } else {
            sD[1][t] = 1e9f; sRC[1][t] = 0.0f; sJ[1][t] = 0; sA[1][t] = 0; sI[1][t] = 0;
        }
    }
    __syncthreads();

    // --- phase B: gather xv1, GEMM1(tile0) -> H ---
    bf16x8 xv1[4];
#pragma unroll
    for (int r = 0; r < 4; r++)
        xv1[r] = *(const bf16x8*)&xg[(size_t)sJ[1][e0 + r] * NB + col * 8];
    {
        bf16x8 a1 = *(bf16x8*)&fA[mrow * EPAD + quad * 8];
        f32x4 acc[8];
#pragma unroll
        for (int nt = 0; nt < 8; nt++) {
            bf16x8 b = *(const bf16x8*)&W1T[(nt * 16 + col) * NR + quad * 8];
            acc[nt] = __builtin_amdgcn_mfma_f32_16x16x32_bf16(a1, b, (f32x4){0.f, 0.f, 0.f, 0.f}, 0, 0, 0);
        }
#pragma unroll
        for (int nt = 0; nt < 8; nt++) {
            int n = nt * 16 + col;
            float bias = b1[n];
#pragma unroll
            for (int r = 0; r < 4; r++) {
                int m = wid * 16 + quad * 4 + r;
                H[m * HPAD + n] = f2bs(ssp_f(acc[nt][r] + bias));
            }
        }
    }
    __syncthreads();

    // --- phase C: GEMM2(tile0) + epilogue0 ; fA(tile1) ---
    {
        f32x4 acc2[8] = {};
#pragma unroll
        for (int kt = 0; kt < 4; kt++) {
            bf16x8 a = *(bf16x8*)&H[mrow * HPAD + kt * 32 + quad * 8];
#pragma unroll
            for (int nt = 0; nt < 8; nt++) {
                bf16x8 b = *(const bf16x8*)&W2T[(nt * 16 + col) * NB + kt * 32 + quad * 8];
                acc2[nt] = __builtin_amdgcn_mfma_f32_16x16x32_bf16(a, b, acc2[nt], 0, 0, 0);
            }
        }
        int cur = sI[0][e0];
        float accum[8] = {0.f, 0.f, 0.f, 0.f, 0.f, 0.f, 0.f, 0.f};
#pragma unroll
        for (int r = 0; r < 4; r++) {
            int el = e0 + r;
            int ii = sI[0][el];
            float rc = sRC[0][el];
            if (ii != cur) {
                flush_pk(agg + (size_t)cur * NB, accum, col);
#pragma unroll
                for (int nt = 0; nt < 8; nt++) accum[nt] = 0.f;
                cur = ii;
            }
#pragma unroll
            for (int nt = 0; nt < 8; nt++) {
                float w = (acc2[nt][r] + b2v[nt]) * rc;
                accum[nt] = fmaf(w, bs2f((unsigned short)xv0[r][nt]), accum[nt]);
            }
        }
        flush_pk(agg + (size_t)cur * NB, accum, col);
    }
    {
        int e_loc = t >> 2;
        int r0 = (t & 3) * 8;
        short v[8];
        if (base1 + e_loc < cnt) {
            float d = sD[1][e_loc];
            const float* em = edge_emb + sA[1][e_loc] * NR + r0;
#pragma unroll
            for (int j = 0; j < 8; j++) {
                float off = (float)(r0 + j) * RBF_STEP;
                float dd = d - off;
                v[j] = f2bs(__expf(RBF_COEFF * dd * dd) + em[j]);
            }
        } else {
#pragma unroll
            for (int j = 0; j < 8; j++) v[j] = 0;
        }
        *(bf16x8*)&fA[e_loc * EPAD + r0] = *(bf16x8*)v;
    }
    __syncthreads();

    if (base1 >= cnt) return;   // block-uniform: tile1 empty

    // --- phase D: GEMM1(tile1) -> H ---
    {
        bf16x8 a1 = *(bf16x8*)&fA[mrow * EPAD + quad * 8];
        f32x4 acc[8];
#pragma unroll
        for (int nt = 0; nt < 8; nt++) {
            bf16x8 b = *(const bf16x8*)&W1T[(nt * 16 + col) * NR + quad * 8];
            acc[nt] = __builtin_amdgcn_mfma_f32_16x16x32_bf16(a1, b, (f32x4){0.f, 0.f, 0.f, 0.f}, 0, 0, 0);
        }
#pragma unroll
        for (int nt = 0; nt < 8; nt++) {
            int n = nt * 16 + col;
            float bias = b1[n];
#pragma unroll
            for (int r = 0; r < 4; r++) {
                int m = wid * 16 + quad * 4 + r;
                H[m * HPAD + n] = f2bs(ssp_f(acc[nt][r] + bias));
            }
        }
    }
    __syncthreads();

    // --- phase E: GEMM2(tile1) + epilogue1 ---
    {
        f32x4 acc2[8] = {};
#pragma unroll
        for (int kt = 0; kt < 4; kt++) {
            bf16x8 a = *(bf16x8*)&H[mrow * HPAD + kt * 32 + quad * 8];
#pragma unroll
            for (int nt = 0; nt < 8; nt++) {
                bf16x8 b = *(const bf16x8*)&W2T[(nt * 16 + col) * NB + kt * 32 + quad * 8];
                acc2[nt] = __builtin_amdgcn_mfma_f32_16x16x32_bf16(a, b, acc2[nt], 0, 0, 0);
            }
        }
        int cur = sI[1][e0];
        float accum[8] = {0.f, 0.f, 0.f, 0.f, 0.f, 0.f, 0.f, 0.f};
#pragma unroll
        for (int r = 0; r < 4; r++) {
            int el = e0 + r;
            int ii = sI[1][el];
            float rc = sRC[1][el];
            if (ii != cur) {
                flush_pk(agg + (size_t)cur * NB, accum, col);
#pragma unroll
                for (int nt = 0; nt < 8; nt++) accum[nt] = 0.f;
                cur = ii;
            }
#pragma unroll
            for (int nt = 0; nt < 8; nt++) {
                float w = (acc2[nt][r] + b2v[nt]) * rc;
                accum[nt] = fmaf(w, bs2f((unsigned short)xv1[r][nt]), accum[nt]);
            }
        }
        flush_pk(agg + (size_t)cur * NB, accum, col);
    }
}

// ---------------------------------------------------------------------------
extern "C" void kernel_launch(void* const* d_in, const int* in_sizes, int n_in,
                              void* d_out, int out_size, void* d_ws, size_t ws_size,
                              hipStream_t stream) {
    const int*   z        = (const int*)d_in[0];
    const int*   z_res    = (const int*)d_in[1];
    const float* pos      = (const float*)d_in[2];
    const int*   idx_i    = (const int*)d_in[3];
    const int*   idx_j    = (const int*)d_in[4];
    const int*   edge_attr= (const int*)d_in[5];
    const int*   batch    = (const int*)d_in[6];
    const float* ele_emb  = (const float*)d_in[7];
    const float* res_emb  = (const float*)d_in[8];
    const float* edge_emb = (const float*)d_in[9];
    const float* in2f_W   = (const float*)d_in[10];
    const float* filt_W1  = (const float*)d_in[11];
    const float* filt_b1  = (const float*)d_in[12];
    const float* filt_W2  = (const float*)d_in[13];
    const float* filt_b2  = (const float*)d_in[14];
    const float* f2out_W1 = (const float*)d_in[15];
    const float* f2out_b1 = (const float*)d_in[16];
    const float* f2out_W2 = (const float*)d_in[17];
    const float* f2out_b2 = (const float*)d_in[18];
    const float* head_W1  = (const float*)d_in[19];
    const float* head_b1  = (const float*)d_in[20];
    const float* head_W2  = (const float*)d_in[21];

    const int N = in_sizes[0];
    const int E = in_sizes[3];

    char* p = (char*)d_ws;
    size_t off = 0;
    auto carve = [&](size_t bytes) -> void* {
        void* q = p + off;
        off = (off + bytes + 255) & ~(size_t)255;
        return q;
    };
    float*  d_d      = (float*)carve((size_t)E * 4);
    float4* edata    = (float4*)carve((size_t)E * 16);
    int*    sIarr    = (int*)carve((size_t)E * 4);
    int*    hist     = (int*)carve((size_t)N * 4);
    int*    cursor   = (int*)carve((size_t)N * 4);
    float*  x_buf    = (float*)carve((size_t)N * NB * 4);
    short*  xf_buf   = (short*)carve((size_t)N * NB * 2);
    short*  agg      = (short*)carve((size_t)N * NB * 2);
    short*  in2f_WT  = (short*)carve((size_t)6 * NB * NB * 2);
    short*  fW1T     = (short*)carve((size_t)6 * NR * NB * 2);
    short*  fW2T     = (short*)carve((size_t)6 * NB * NB * 2);
    short*  oW1T     = (short*)carve((size_t)6 * NB * NB * 2);
    short*  oW2T     = (short*)carve((size_t)6 * NB * NB * 2);
    short*  hW1T     = (short*)carve((size_t)NB * NB * 2);
    (void)ws_size;

    // weight prep (bf16 transposed)
    {
        int tot = 6 * NB * NB;
        transpose_cvt<<<(tot + 255) / 256, 256, 0, stream>>>(in2f_W, in2f_WT, NB, NB, tot);
        transpose_cvt<<<(tot + 255) / 256, 256, 0, stream>>>(filt_W2, fW2T, NB, NB, tot);
        transpose_cvt<<<(tot + 255) / 256, 256, 0, stream>>>(f2out_W1, oW1T, NB, NB, tot);
        transpose_cvt<<<(tot + 255) / 256, 256, 0, stream>>>(f2out_W2, oW2T, NB, NB, tot);
        int tot1 = 6 * NR * NB;
        transpose_cvt<<<(tot1 + 255) / 256, 256, 0, stream>>>(filt_W1, fW1T, NR, NB, tot1);
        int tot2 = NB * NB;
        transpose_cvt<<<(tot2 + 255) / 256, 256, 0, stream>>>(head_W1, hW1T, NB, NB, tot2);
    }

    // edge prep + idx_i-grouped sort with packed records
    hipMemsetAsync(hist, 0, (size_t)N * 4, stream);
    int nblk_e4 = (E + 1023) / 1024;
    edge_prep4<<<nblk_e4, 256, 0, stream>>>(pos, idx_i, idx_j, d_d, hist, E);
    scan_hist<<<1, 1024, 0, stream>>>(hist, cursor, N);
    scatter_sorted4<<<nblk_e4, 256, 0, stream>>>(d_d, idx_i, idx_j, edge_attr,
                                                 cursor, edata, sIarr, E);
    // cursor[a] is now the END of atom a's sorted range; cursor[N-1] = count.

    atom_embed<<<(N * NB + 255) / 256, 256, 0, stream>>>(z, z_res, ele_emb, res_emb, x_buf, N);

    int nblk_atom64 = (N + 63) / 64;
    int nblk_edge2 = (E + 127) / 128;

    node_in2f_mfma<<<nblk_atom64, 256, 0, stream>>>(x_buf, in2f_WT, xf_buf, N);
    hipMemsetAsync(d_out, 0, (size_t)out_size * sizeof(float), stream);
    hipMemsetAsync(agg, 0, (size_t)N * NB * 2, stream);   // once; node_fused re-zeroes
    for (int i = 0; i < 6; i++) {
        edge_fused_mfma2<<<nblk_edge2, 256, 0, stream>>>(
            edata, sIarr, cursor, N, edge_emb,
            fW1T + (size_t)i * NR * NB, filt_b1 + (size_t)i * NB,
            fW2T + (size_t)i * NB * NB, filt_b2 + (size_t)i * NB,
            xf_buf, agg);
        if (i < 5) {
            node_fused_mfma<<<nblk_atom64, 256, 0, stream>>>(
                agg, oW1T + (size_t)i * NB * NB, f2out_b1 + (size_t)i * NB,
                oW2T + (size_t)i * NB * NB, f2out_b2 + (size_t)i * NB,
                in2f_WT + (size_t)(i + 1) * NB * NB,
                x_buf, xf_buf, N);
        } else {
            node_out_head_mfma<<<nblk_atom64, 256, 0, stream>>>(
                agg, oW1T + (size_t)i * NB * NB, f2out_b1 + (size_t)i * NB,
                oW2T + (size_t)i * NB * NB, f2out_b2 + (size_t)i * NB,
                x_buf, batch, hW1T, head_b1, head_W2,
                (float*)d_out, N);
        }
    }
}

// Round 15
// 2354.745 us; speedup vs baseline: 1.0475x; 1.0475x over previous
//
#include <hip/hip_runtime.h>
#include <hip/hip_bf16.h>
#include <math.h>

#define NB 128
#define NR 32
#define EPAD 40    // fA row stride in shorts
#define HPAD 136   // H/XA row stride in shorts (272B, 16B-aligned rows)

// FINAL (r15 = r13 = r11): best-confirmed configuration, 2355 us.
// xf layout: feature-permuted (storage col c = col*8 + nt holds feature
// nt*16+col) -> one bf16x8 load per edge per lane. agg: ORIGINAL feature
// order, bf16, packed-bf16 atomics (2 features/4B op), merged equal-atom runs.
// Falsified alternatives: r5 LDS gather staging (occupancy), r6 owner-computes
// fusion (occupancy+spill), r7 permuted scatter (write amplification),
// r10 pre-barrier gather (redundant loads), r12 analytic A-fragment (not
// LDS-limited), r14 2-tile pipeline (atomic L2 locality loss).

static constexpr float CUTOFF_F    = 10.0f;
static constexpr float RBF_STEP    = 10.0f / 31.0f;
static constexpr float RBF_COEFF   = -4.805f;           // -0.5/(10/31)^2
static constexpr float LOG2_F      = 0.69314718055994531f;
static constexpr float PI_OVER_CUT = 0.314159265358979f;

typedef __attribute__((ext_vector_type(8))) short bf16x8;
typedef __attribute__((ext_vector_type(2))) short bf16x2;
typedef __attribute__((ext_vector_type(4))) float f32x4;

__device__ __forceinline__ short f2bs(float x) {
    __hip_bfloat16 h = __float2bfloat16(x);   // RNE
    return *reinterpret_cast<short*>(&h);
}
__device__ __forceinline__ float bs2f(unsigned short u) {
    unsigned int v = ((unsigned int)u) << 16;
    return __uint_as_float(v);
}
__device__ __forceinline__ float ssp_f(float v) {
    return fmaxf(v, 0.0f) + __logf(1.0f + __expf(-fabsf(v))) - LOG2_F;
}
__device__ __forceinline__ float silu_f(float v) {
    return v / (1.0f + __expf(-v));
}

// packed bf16 atomic add (2 features per op)
__device__ __forceinline__ void atomic_pk_add_bf16(short* addr, float lo, float hi) {
#if __has_builtin(__builtin_amdgcn_global_atomic_fadd_v2bf16)
    typedef bf16x2 __attribute__((address_space(1))) *gptr;
    bf16x2 v;
    v[0] = f2bs(lo);
    v[1] = f2bs(hi);
    __builtin_amdgcn_global_atomic_fadd_v2bf16((gptr)(unsigned long long)addr, v);
#else
    unsigned int* w = (unsigned int*)addr;
    unsigned int old = *w, assumed;
    do {
        assumed = old;
        float fl = bs2f((unsigned short)(assumed & 0xffff)) + lo;
        float fh = bs2f((unsigned short)(assumed >> 16)) + hi;
        unsigned int nv = ((unsigned int)(unsigned short)f2bs(fh) << 16) |
                          (unsigned short)f2bs(fl);
        old = atomicCAS(w, assumed, nv);
    } while (old != assumed);
#endif
}

// flush one merged run: 8 accumulated features/lane -> 4 pk atomics/lane.
// Run boundaries are quad-uniform so the lane^1 shuffles pair active lanes.
__device__ __forceinline__ void flush_pk(short* aggrow, const float* accum, int col) {
    bool even = ((col & 1) == 0);
#pragma unroll
    for (int q = 0; q < 4; q++) {
        float a = accum[2 * q], b = accum[2 * q + 1];
        float pa = __shfl_xor(a, 1);   // feature (2q)*16 + (col^1)
        float pb = __shfl_xor(b, 1);
        int nbase = even ? (2 * q) * 16 + col : (2 * q + 1) * 16 + (col - 1);
        float lo = even ? a : pb;
        float hi = even ? pa : b;
        atomic_pk_add_bf16(aggrow + nbase, lo, hi);
    }
}

// ---------------------------------------------------------------------------
// Weight prep: dst[b][c][r] = bf16(src[b][r][c])
// ---------------------------------------------------------------------------
__global__ void transpose_cvt(const float* __restrict__ src, short* __restrict__ dst,
                              int R, int C, int total) {
    int t = blockIdx.x * blockDim.x + threadIdx.x;
    if (t >= total) return;
    int rc = R * C;
    int b = t / rc;
    int rem = t - b * rc;
    int c = rem / R;
    int r = rem - c * R;
    dst[t] = f2bs(src[(size_t)b * rc + (size_t)r * C + c]);
}

// ---------------------------------------------------------------------------
// Edge prep: distances + per-atom histogram. 4 edges/thread for MLP.
// ---------------------------------------------------------------------------
__global__ void edge_prep4(const float* __restrict__ pos,
                           const int* __restrict__ idx_i,
                           const int* __restrict__ idx_j,
                           float* __restrict__ d_ij,
                           int* __restrict__ hist,
                           int E) {
    int b0 = blockIdx.x * 1024 + threadIdx.x;
    int ia[4], ib[4];
    bool val[4];
#pragma unroll
    for (int k = 0; k < 4; k++) {
        int e = b0 + k * 256;
        val[k] = (e < E);
        ia[k] = val[k] ? idx_i[e] : 0;
        ib[k] = val[k] ? idx_j[e] : 0;
    }
    float ax[4], ay[4], az[4], bx[4], by[4], bz[4];
#pragma unroll
    for (int k = 0; k < 4; k++) {
        const float* pa = pos + ia[k] * 3;
        ax[k] = pa[0]; ay[k] = pa[1]; az[k] = pa[2];
    }
#pragma unroll
    for (int k = 0; k < 4; k++) {
        const float* pb = pos + ib[k] * 3;
        bx[k] = pb[0]; by[k] = pb[1]; bz[k] = pb[2];
    }
#pragma unroll
    for (int k = 0; k < 4; k++) {
        if (!val[k]) continue;
        float dx = ax[k] - bx[k], dy = ay[k] - by[k], dz = az[k] - bz[k];
        float d = sqrtf(dx * dx + dy * dy + dz * dz);
        d_ij[b0 + k * 256] = d;
        if (d < CUTOFF_F) atomicAdd(&hist[ia[k]], 1);
    }
}

// ---------------------------------------------------------------------------
// Single-block exclusive scan of hist[N] -> cursor[N]  (1024 threads).
// ---------------------------------------------------------------------------
__global__ __launch_bounds__(1024) void scan_hist(const int* __restrict__ hist,
                                                  int* __restrict__ cursor, int N) {
    __shared__ int part[1024];
    int t = threadIdx.x;
    int chunk = (N + 1023) / 1024;
    int lo = t * chunk;
    int hi = min(lo + chunk, N);
    int s = 0;
    for (int i = lo; i < hi; i++) s += hist[i];
    part[t] = s;
    __syncthreads();
    for (int d = 1; d < 1024; d <<= 1) {
        int v = (t >= d) ? part[t - d] : 0;
        __syncthreads();
        part[t] += v;
        __syncthreads();
    }
    int run = (t == 0) ? 0 : part[t - 1];
    for (int i = lo; i < hi; i++) {
        cursor[i] = run;
        run += hist[i];
    }
}

// ---------------------------------------------------------------------------
// Scatter active edges into idx_i-grouped order. 4 edges/thread for MLP.
// Computes rcut for active edges only. After: cursor[a] == end of range.
// ---------------------------------------------------------------------------
__global__ void scatter_sorted4(const float* __restrict__ d_ij,
                                const int* __restrict__ idx_i,
                                const int* __restrict__ idx_j,
                                const int* __restrict__ edge_attr,
                                int* __restrict__ cursor,
                                float4* __restrict__ edata,
                                int* __restrict__ sIarr, int E) {
    int b0 = blockIdx.x * 1024 + threadIdx.x;
    float d[4]; int ii[4], jj[4], at[4]; bool act[4];
#pragma unroll
    for (int k = 0; k < 4; k++) {
        int e = b0 + k * 256;
        bool v = (e < E);
        d[k] = v ? d_ij[e] : 1e9f;
        act[k] = (d[k] < CUTOFF_F);
        ii[k] = act[k] ? idx_i[e] : 0;
        jj[k] = act[k] ? idx_j[e] : 0;
        at[k] = act[k] ? edge_attr[e] : 0;
    }
    int p[4];
#pragma unroll
    for (int k = 0; k < 4; k++)
        if (act[k]) p[k] = atomicAdd(&cursor[ii[k]], 1);
#pragma unroll
    for (int k = 0; k < 4; k++) {
        if (!act[k]) continue;
        float4 v;
        v.x = d[k];
        v.y = 0.5f * (__cosf(d[k] * PI_OVER_CUT) + 1.0f);
        v.z = __int_as_float(jj[k]);
        v.w = __int_as_float(at[k]);
        edata[p[k]] = v;
        sIarr[p[k]] = ii[k];
    }
}

// ---------------------------------------------------------------------------
// x = ele_emb[z] + res_emb[z_res]
// ---------------------------------------------------------------------------
__global__ void atom_embed(const int* __restrict__ z,
                           const int* __restrict__ z_res,
                           const float* __restrict__ ele_emb,
                           const float* __restrict__ res_emb,
                           float* __restrict__ x, int N) {
    int t = blockIdx.x * blockDim.x + threadIdx.x;
    if (t >= N * NB) return;
    int n = t >> 7, c = t & 127;
    x[t] = ele_emb[z[n] * NB + c] + res_emb[z_res[n] * NB + c];
}

// ---------------------------------------------------------------------------
// xf(bf16, permuted cols) = in(fp32) @ W  via MFMA. First-iteration in2f.
// ---------------------------------------------------------------------------
__global__ __launch_bounds__(256, 4) void node_in2f_mfma(
    const float* __restrict__ x, const short* __restrict__ WT,
    short* __restrict__ xf, int N) {
    __shared__ __align__(16) short XA[64 * HPAD];
    int a0 = blockIdx.x * 64;
    int t = threadIdx.x;
#pragma unroll
    for (int c = 0; c < 4; c++) {
        int chunk = t + c * 256;
        int row = chunk >> 4;
        int col = (chunk & 15) * 8;
        short v[8];
        if (a0 + row < N) {
            const float* src = x + (size_t)(a0 + row) * NB + col;
            float4 f0 = *(const float4*)src;
            float4 f1 = *(const float4*)(src + 4);
            v[0] = f2bs(f0.x); v[1] = f2bs(f0.y); v[2] = f2bs(f0.z); v[3] = f2bs(f0.w);
            v[4] = f2bs(f1.x); v[5] = f2bs(f1.y); v[6] = f2bs(f1.z); v[7] = f2bs(f1.w);
        } else {
#pragma unroll
            for (int j = 0; j < 8; j++) v[j] = 0;
        }
        *(bf16x8*)&XA[row * HPAD + col] = *(bf16x8*)v;
    }
    __syncthreads();

    int wid = t >> 6, lane = t & 63;
    int quad = lane >> 4, col = lane & 15;
    int mrow = wid * 16 + col;

    f32x4 acc[8] = {};
#pragma unroll
    for (int kt = 0; kt < 4; kt++) {
        bf16x8 a = *(bf16x8*)&XA[mrow * HPAD + kt * 32 + quad * 8];
#pragma unroll
        for (int nt = 0; nt < 8; nt++) {
            bf16x8 b = *(const bf16x8*)&WT[(nt * 16 + col) * NB + kt * 32 + quad * 8];
            acc[nt] = __builtin_amdgcn_mfma_f32_16x16x32_bf16(a, b, acc[nt], 0, 0, 0);
        }
    }
#pragma unroll
    for (int nt = 0; nt < 8; nt++) {
        int cst = col * 8 + nt;   // permuted storage col
#pragma unroll
        for (int r = 0; r < 4; r++) {
            int m = wid * 16 + quad * 4 + r;
            if (a0 + m < N) xf[(size_t)(a0 + m) * NB + cst] = f2bs(acc[nt][r]);
        }
    }
}

// ---------------------------------------------------------------------------
// Fused: v = ssp(agg@W1+b1)@W2+b2 ; x += v ; xf_next(bf16, permuted) = x @ Wn
// agg is bf16 in ORIGINAL feature order. After staging agg, this kernel
// re-zeroes its agg rows (replaces the inter-iteration memset).
// ---------------------------------------------------------------------------
__global__ __launch_bounds__(256, 4) void node_fused_mfma(
    short* __restrict__ agg,
    const short* __restrict__ W1T, const float* __restrict__ b1,
    const short* __restrict__ W2T, const float* __restrict__ b2,
    const short* __restrict__ WnT,
    float* __restrict__ x, short* __restrict__ xf, int N) {
    __shared__ __align__(16) short XA[64 * HPAD];
    __shared__ __align__(16) short H[64 * HPAD];
    int a0 = blockIdx.x * 64;
    int t = threadIdx.x;
#pragma unroll
    for (int c = 0; c < 4; c++) {
        int chunk = t + c * 256;
        int row = chunk >> 4;
        int col = (chunk & 15) * 8;
        bf16x8 v = {0, 0, 0, 0, 0, 0, 0, 0};
        if (a0 + row < N) {
            short* src = agg + (size_t)(a0 + row) * NB + col;
            v = *(const bf16x8*)src;
            *(bf16x8*)src = (bf16x8){0, 0, 0, 0, 0, 0, 0, 0};  // re-zero for next iter
        }
        *(bf16x8*)&XA[row * HPAD + col] = v;
    }
    __syncthreads();

    int wid = t >> 6, lane = t & 63;
    int quad = lane >> 4, col = lane & 15;
    int mrow = wid * 16 + col;

    // GEMM1 + ssp -> H
    {
        f32x4 acc[8] = {};
#pragma unroll
        for (int kt = 0; kt < 4; kt++) {
            bf16x8 a = *(bf16x8*)&XA[mrow * HPAD + kt * 32 + quad * 8];
#pragma unroll
            for (int nt = 0; nt < 8; nt++) {
                bf16x8 b = *(const bf16x8*)&W1T[(nt * 16 + col) * NB + kt * 32 + quad * 8];
                acc[nt] = __builtin_amdgcn_mfma_f32_16x16x32_bf16(a, b, acc[nt], 0, 0, 0);
            }
        }
#pragma unroll
        for (int nt = 0; nt < 8; nt++) {
            int n = nt * 16 + col;
            float bias = b1[n];
#pragma unroll
            for (int r = 0; r < 4; r++) {
                int m = wid * 16 + quad * 4 + r;
                H[m * HPAD + n] = f2bs(ssp_f(acc[nt][r] + bias));
            }
        }
    }
    __syncthreads();

    // GEMM2 + residual: x_new -> global fp32 + XA bf16 (reuse)
    {
        f32x4 acc[8] = {};
#pragma unroll
        for (int kt = 0; kt < 4; kt++) {
            bf16x8 a = *(bf16x8*)&H[mrow * HPAD + kt * 32 + quad * 8];
#pragma unroll
            for (int nt = 0; nt < 8; nt++) {
                bf16x8 b = *(const bf16x8*)&W2T[(nt * 16 + col) * NB + kt * 32 + quad * 8];
                acc[nt] = __builtin_amdgcn_mfma_f32_16x16x32_bf16(a, b, acc[nt], 0, 0, 0);
            }
        }
#pragma unroll
        for (int nt = 0; nt < 8; nt++) {
            int n = nt * 16 + col;
            float bias = b2[n];
#pragma unroll
            for (int r = 0; r < 4; r++) {
                int m = wid * 16 + quad * 4 + r;
                float xn = 0.0f;
                if (a0 + m < N) {
                    size_t o = (size_t)(a0 + m) * NB + n;
                    xn = x[o] + acc[nt][r] + bias;
                    x[o] = xn;
                }
                XA[m * HPAD + n] = f2bs(xn);
            }
        }
    }
    __syncthreads();

    // GEMM3: xf = x_new @ Wn  (bf16 out, permuted storage cols)
    {
        f32x4 acc[8] = {};
#pragma unroll
        for (int kt = 0; kt < 4; kt++) {
            bf16x8 a = *(bf16x8*)&XA[mrow * HPAD + kt * 32 + quad * 8];
#pragma unroll
            for (int nt = 0; nt < 8; nt++) {
                bf16x8 b = *(const bf16x8*)&WnT[(nt * 16 + col) * NB + kt * 32 + quad * 8];
                acc[nt] = __builtin_amdgcn_mfma_f32_16x16x32_bf16(a, b, acc[nt], 0, 0, 0);
            }
        }
#pragma unroll
        for (int nt = 0; nt < 8; nt++) {
            int cst = col * 8 + nt;
#pragma unroll
            for (int r = 0; r < 4; r++) {
                int m = wid * 16 + quad * 4 + r;
                if (a0 + m < N) xf[(size_t)(a0 + m) * NB + cst] = f2bs(acc[nt][r]);
            }
        }
    }
}

// ---------------------------------------------------------------------------
// Last iteration fused with head: v = ssp(agg@W1+b1)@W2+b2 ; xn = x + v ;
// h = silu(xn/||xn||) ; silu(h@hW1+hb1)@hW2 ; segment-sum by batch.
// ---------------------------------------------------------------------------
__global__ __launch_bounds__(256, 4) void node_out_head_mfma(
    const short* __restrict__ agg,
    const short* __restrict__ W1T, const float* __restrict__ b1,
    const short* __restrict__ W2T, const float* __restrict__ b2,
    const float* __restrict__ x, const int* __restrict__ batch,
    const short* __restrict__ hW1T, const float* __restrict__ hb1,
    const float* __restrict__ hW2,
    float* __restrict__ out, int N) {
    __shared__ __align__(16) short XA[64 * HPAD];
    __shared__ __align__(16) short H[64 * HPAD];
    __shared__ int sbat[64];
    __shared__ float rowval[64];
    int a0 = blockIdx.x * 64;
    int t = threadIdx.x;

    if (t < 64) sbat[t] = (a0 + t < N) ? batch[a0 + t] : -1;
#pragma unroll
    for (int c = 0; c < 4; c++) {
        int chunk = t + c * 256;
        int row = chunk >> 4;
        int col = (chunk & 15) * 8;
        bf16x8 v = {0, 0, 0, 0, 0, 0, 0, 0};
        if (a0 + row < N) v = *(const bf16x8*)&agg[(size_t)(a0 + row) * NB + col];
        *(bf16x8*)&XA[row * HPAD + col] = v;
    }
    __syncthreads();

    int wid = t >> 6, lane = t & 63;
    int quad = lane >> 4, col = lane & 15;
    int mrow = wid * 16 + col;

    // GEMM1 + ssp -> H
    {
        f32x4 acc[8] = {};
#pragma unroll
        for (int kt = 0; kt < 4; kt++) {
            bf16x8 a = *(bf16x8*)&XA[mrow * HPAD + kt * 32 + quad * 8];
#pragma unroll
            for (int nt = 0; nt < 8; nt++) {
                bf16x8 b = *(const bf16x8*)&W1T[(nt * 16 + col) * NB + kt * 32 + quad * 8];
                acc[nt] = __builtin_amdgcn_mfma_f32_16x16x32_bf16(a, b, acc[nt], 0, 0, 0);
            }
        }
#pragma unroll
        for (int nt = 0; nt < 8; nt++) {
            int n = nt * 16 + col;
            float bias = b1[n];
#pragma unroll
            for (int r = 0; r < 4; r++) {
                int m = wid * 16 + quad * 4 + r;
                H[m * HPAD + n] = f2bs(ssp_f(acc[nt][r] + bias));
            }
        }
    }
    __syncthreads();

    // GEMM2 + residual in registers; row sums of squares via 16-lane shuffle
    float xnv[8][4];
    float ssq[4] = {0.f, 0.f, 0.f, 0.f};
    {
        f32x4 acc[8] = {};
#pragma unroll
        for (int kt = 0; kt < 4; kt++) {
            bf16x8 a = *(bf16x8*)&H[mrow * HPAD + kt * 32 + quad * 8];
#pragma unroll
            for (int nt = 0; nt < 8; nt++) {
                bf16x8 b = *(const bf16x8*)&W2T[(nt * 16 + col) * NB + kt * 32 + quad * 8];
                acc[nt] = __builtin_amdgcn_mfma_f32_16x16x32_bf16(a, b, acc[nt], 0, 0, 0);
            }
        }
#pragma unroll
        for (int nt = 0; nt < 8; nt++) {
            int n = nt * 16 + col;
            float bias = b2[n];
#pragma unroll
            for (int r = 0; r < 4; r++) {
                int m = wid * 16 + quad * 4 + r;
                float xn = 0.0f;
                if (a0 + m < N) xn = x[(size_t)(a0 + m) * NB + n] + acc[nt][r] + bias;
                xnv[nt][r] = xn;
                ssq[r] += xn * xn;
            }
        }
    }
#pragma unroll
    for (int r = 0; r < 4; r++) {
#pragma unroll
        for (int m = 1; m < 16; m <<= 1) ssq[r] += __shfl_xor(ssq[r], m);
    }
    float inv[4];
#pragma unroll
    for (int r = 0; r < 4; r++) inv[r] = 1.0f / fmaxf(sqrtf(ssq[r]), 1e-12f);
    __syncthreads();
#pragma unroll
    for (int nt = 0; nt < 8; nt++) {
        int n = nt * 16 + col;
#pragma unroll
        for (int r = 0; r < 4; r++) {
            int m = wid * 16 + quad * 4 + r;
            XA[m * HPAD + n] = f2bs(silu_f(xnv[nt][r] * inv[r]));
        }
    }
    __syncthreads();

    // head GEMM: silu(h@hW1+hb1) dot hW2 per row
    f32x4 acc[8] = {};
#pragma unroll
    for (int kt = 0; kt < 4; kt++) {
        bf16x8 a = *(bf16x8*)&XA[mrow * HPAD + kt * 32 + quad * 8];
#pragma unroll
        for (int nt = 0; nt < 8; nt++) {
            bf16x8 b = *(const bf16x8*)&hW1T[(nt * 16 + col) * NB + kt * 32 + quad * 8];
            acc[nt] = __builtin_amdgcn_mfma_f32_16x16x32_bf16(a, b, acc[nt], 0, 0, 0);
        }
    }
    float partial[4] = {0.f, 0.f, 0.f, 0.f};
#pragma unroll
    for (int nt = 0; nt < 8; nt++) {
        int n = nt * 16 + col;
        float bias = hb1[n];
        float w2 = hW2[n];
#pragma unroll
        for (int r = 0; r < 4; r++) partial[r] += silu_f(acc[nt][r] + bias) * w2;
    }
#pragma unroll
    for (int r = 0; r < 4; r++) {
#pragma unroll
        for (int d = 1; d < 16; d <<= 1) partial[r] += __shfl_xor(partial[r], d);
    }
    if (col == 0) {
#pragma unroll
        for (int r = 0; r < 4; r++) rowval[wid * 16 + quad * 4 + r] = partial[r];
    }
    __syncthreads();

    if (t < 64) {
        int b = sbat[t];
        bool headf = (b >= 0) && (t == 0 || sbat[t - 1] != b);
        if (headf) {
            float s = 0.0f;
            int rr = t;
            while (rr < 64 && sbat[rr] == b) { s += rowval[rr]; rr++; }
            atomicAdd(&out[b], s);
        }
    }
}

// ---------------------------------------------------------------------------
// Fused edge filter (MFMA) + vectorized bf16x8 gather (permuted xf layout,
// post-barrier placement) + merged packed-bf16 atomic scatter. 64 edges/blk.
// ---------------------------------------------------------------------------
__global__ __launch_bounds__(256, 4) void edge_fused_mfma(
    const float4* __restrict__ edata, const int* __restrict__ sIarr,
    const int* __restrict__ rowend, int natoms,
    const float* __restrict__ edge_emb,
    const short* __restrict__ W1T, const float* __restrict__ b1,
    const short* __restrict__ W2T, const float* __restrict__ b2,
    const short* __restrict__ xf, short* __restrict__ agg) {
    __shared__ __align__(16) short fA[64 * EPAD];
    __shared__ __align__(16) short H[64 * HPAD];
    __shared__ float sD[64], sRC[64];
    __shared__ int sI[64], sJ[64], sA[64];

    int cnt = rowend[natoms - 1];
    int base = blockIdx.x * 64;
    if (base >= cnt) return;
    int t = threadIdx.x;

    if (t < 64) {
        int ei = base + t;
        if (ei < cnt) {
            float4 v = edata[ei];
            sD[t] = v.x;
            sRC[t] = v.y;
            sJ[t] = __float_as_int(v.z);
            sA[t] = __float_as_int(v.w);
            sI[t] = sIarr[ei];
        } else {
            sD[t] = 1e9f; sRC[t] = 0.0f; sJ[t] = 0; sA[t] = 0; sI[t] = 0;
        }
    }
    __syncthreads();

    int wid = t >> 6, lane = t & 63;
    int quad = lane >> 4, col = lane & 15;
    int mrow = wid * 16 + col;
    int e0 = wid * 16 + quad * 4;

    // vectorized gather (permuted xf): one bf16x8 (16B) per edge delivers
    // exactly features {nt*16+col}; issued here to overlap RBF + GEMM1.
    bf16x8 xv[4];
    const unsigned short* xg = (const unsigned short*)xf;
#pragma unroll
    for (int r = 0; r < 4; r++)
        xv[r] = *(const bf16x8*)&xg[(size_t)sJ[e0 + r] * NB + col * 8];

    // stage A: f_ij tile (RBF + edge_emb), bf16
    {
        int e_loc = t >> 2;
        int r0 = (t & 3) * 8;
        short v[8];
        if (base + e_loc < cnt) {
            float d = sD[e_loc];
            const float* em = edge_emb + sA[e_loc] * NR + r0;
#pragma unroll
            for (int j = 0; j < 8; j++) {
                float off = (float)(r0 + j) * RBF_STEP;
                float dd = d - off;
                v[j] = f2bs(__expf(RBF_COEFF * dd * dd) + em[j]);
            }
        } else {
#pragma unroll
            for (int j = 0; j < 8; j++) v[j] = 0;
        }
        *(bf16x8*)&fA[e_loc * EPAD + r0] = *(bf16x8*)v;
    }
    __syncthreads();

    // GEMM1: hidden = f_ij @ W1 (K=32)
    {
        bf16x8 a1 = *(bf16x8*)&fA[mrow * EPAD + quad * 8];
        f32x4 acc[8];
#pragma unroll
        for (int nt = 0; nt < 8; nt++) {
            bf16x8 b = *(const bf16x8*)&W1T[(nt * 16 + col) * NR + quad * 8];
            acc[nt] = __builtin_amdgcn_mfma_f32_16x16x32_bf16(a1, b, (f32x4){0.f, 0.f, 0.f, 0.f}, 0, 0, 0);
        }
#pragma unroll
        for (int nt = 0; nt < 8; nt++) {
            int n = nt * 16 + col;
            float bias = b1[n];
#pragma unroll
            for (int r = 0; r < 4; r++) {
                int m = wid * 16 + quad * 4 + r;
                H[m * HPAD + n] = f2bs(ssp_f(acc[nt][r] + bias));
            }
        }
    }
    __syncthreads();

    // GEMM2: Wij = hidden @ W2 (K=128)
    f32x4 acc2[8] = {};
#pragma unroll
    for (int kt = 0; kt < 4; kt++) {
        bf16x8 a = *(bf16x8*)&H[mrow * HPAD + kt * 32 + quad * 8];
#pragma unroll
        for (int nt = 0; nt < 8; nt++) {
            bf16x8 b = *(const bf16x8*)&W2T[(nt * 16 + col) * NB + kt * 32 + quad * 8];
            acc2[nt] = __builtin_amdgcn_mfma_f32_16x16x32_bf16(a, b, acc2[nt], 0, 0, 0);
        }
    }

    // epilogue: merge equal-atom runs over this thread's 4 edges, flush each
    // run with 4 packed-bf16 atomics (2 features per 4B op).
    float b2v[8];
#pragma unroll
    for (int nt = 0; nt < 8; nt++) b2v[nt] = b2[nt * 16 + col];

    int cur = sI[e0];
    float accum[8] = {0.f, 0.f, 0.f, 0.f, 0.f, 0.f, 0.f, 0.f};
#pragma unroll
    for (int r = 0; r < 4; r++) {
        int el = e0 + r;
        int ii = sI[el];
        float rc = sRC[el];
        if (ii != cur) {
            flush_pk(agg + (size_t)cur * NB, accum, col);
#pragma unroll
            for (int nt = 0; nt < 8; nt++) accum[nt] = 0.f;
            cur = ii;
        }
#pragma unroll
        for (int nt = 0; nt < 8; nt++) {
            float w = (acc2[nt][r] + b2v[nt]) * rc;
            accum[nt] = fmaf(w, bs2f((unsigned short)xv[r][nt]), accum[nt]);
        }
    }
    flush_pk(agg + (size_t)cur * NB, accum, col);
}

// ---------------------------------------------------------------------------
extern "C" void kernel_launch(void* const* d_in, const int* in_sizes, int n_in,
                              void* d_out, int out_size, void* d_ws, size_t ws_size,
                              hipStream_t stream) {
    const int*   z        = (const int*)d_in[0];
    const int*   z_res    = (const int*)d_in[1];
    const float* pos      = (const float*)d_in[2];
    const int*   idx_i    = (const int*)d_in[3];
    const int*   idx_j    = (const int*)d_in[4];
    const int*   edge_attr= (const int*)d_in[5];
    const int*   batch    = (const int*)d_in[6];
    const float* ele_emb  = (const float*)d_in[7];
    const float* res_emb  = (const float*)d_in[8];
    const float* edge_emb = (const float*)d_in[9];
    const float* in2f_W   = (const float*)d_in[10];
    const float* filt_W1  = (const float*)d_in[11];
    const float* filt_b1  = (const float*)d_in[12];
    const float* filt_W2  = (const float*)d_in[13];
    const float* filt_b2  = (const float*)d_in[14];
    const float* f2out_W1 = (const float*)d_in[15];
    const float* f2out_b1 = (const float*)d_in[16];
    const float* f2out_W2 = (const float*)d_in[17];
    const float* f2out_b2 = (const float*)d_in[18];
    const float* head_W1  = (const float*)d_in[19];
    const float* head_b1  = (const float*)d_in[20];
    const float* head_W2  = (const float*)d_in[21];

    const int N = in_sizes[0];
    const int E = in_sizes[3];

    char* p = (char*)d_ws;
    size_t off = 0;
    auto carve = [&](size_t bytes) -> void* {
        void* q = p + off;
        off = (off + bytes + 255) & ~(size_t)255;
        return q;
    };
    float*  d_d      = (float*)carve((size_t)E * 4);
    float4* edata    = (float4*)carve((size_t)E * 16);
    int*    sIarr    = (int*)carve((size_t)E * 4);
    int*    hist     = (int*)carve((size_t)N * 4);
    int*    cursor   = (int*)carve((size_t)N * 4);
    float*  x_buf    = (float*)carve((size_t)N * NB * 4);
    short*  xf_buf   = (short*)carve((size_t)N * NB * 2);
    short*  agg      = (short*)carve((size_t)N * NB * 2);
    short*  in2f_WT  = (short*)carve((size_t)6 * NB * NB * 2);
    short*  fW1T     = (short*)carve((size_t)6 * NR * NB * 2);
    short*  fW2T     = (short*)carve((size_t)6 * NB * NB * 2);
    short*  oW1T     = (short*)carve((size_t)6 * NB * NB * 2);
    short*  oW2T     = (short*)carve((size_t)6 * NB * NB * 2);
    short*  hW1T     = (short*)carve((size_t)NB * NB * 2);
    (void)ws_size;

    // weight prep (bf16 transposed)
    {
        int tot = 6 * NB * NB;
        transpose_cvt<<<(tot + 255) / 256, 256, 0, stream>>>(in2f_W, in2f_WT, NB, NB, tot);
        transpose_cvt<<<(tot + 255) / 256, 256, 0, stream>>>(filt_W2, fW2T, NB, NB, tot);
        transpose_cvt<<<(tot + 255) / 256, 256, 0, stream>>>(f2out_W1, oW1T, NB, NB, tot);
        transpose_cvt<<<(tot + 255) / 256, 256, 0, stream>>>(f2out_W2, oW2T, NB, NB, tot);
        int tot1 = 6 * NR * NB;
        transpose_cvt<<<(tot1 + 255) / 256, 256, 0, stream>>>(filt_W1, fW1T, NR, NB, tot1);
        int tot2 = NB * NB;
        transpose_cvt<<<(tot2 + 255) / 256, 256, 0, stream>>>(head_W1, hW1T, NB, NB, tot2);
    }

    // edge prep + idx_i-grouped sort with packed records
    hipMemsetAsync(hist, 0, (size_t)N * 4, stream);
    int nblk_e4 = (E + 1023) / 1024;
    edge_prep4<<<nblk_e4, 256, 0, stream>>>(pos, idx_i, idx_j, d_d, hist, E);
    scan_hist<<<1, 1024, 0, stream>>>(hist, cursor, N);
    scatter_sorted4<<<nblk_e4, 256, 0, stream>>>(d_d, idx_i, idx_j, edge_attr,
                                                 cursor, edata, sIarr, E);
    // cursor[a] is now the END of atom a's sorted range; cursor[N-1] = count.

    atom_embed<<<(N * NB + 255) / 256, 256, 0, stream>>>(z, z_res, ele_emb, res_emb, x_buf, N);

    int nblk_atom64 = (N + 63) / 64;
    int nblk_edge = (E + 63) / 64;

    node_in2f_mfma<<<nblk_atom64, 256, 0, stream>>>(x_buf, in2f_WT, xf_buf, N);
    hipMemsetAsync(d_out, 0, (size_t)out_size * sizeof(float), stream);
    hipMemsetAsync(agg, 0, (size_t)N * NB * 2, stream);   // once; node_fused re-zeroes
    for (int i = 0; i < 6; i++) {
        edge_fused_mfma<<<nblk_edge, 256, 0, stream>>>(
            edata, sIarr, cursor, N, edge_emb,
            fW1T + (size_t)i * NR * NB, filt_b1 + (size_t)i * NB,
            fW2T + (size_t)i * NB * NB, filt_b2 + (size_t)i * NB,
            xf_buf, agg);
        if (i < 5) {
            node_fused_mfma<<<nblk_atom64, 256, 0, stream>>>(
                agg, oW1T + (size_t)i * NB * NB, f2out_b1 + (size_t)i * NB,
                oW2T + (size_t)i * NB * NB, f2out_b2 + (size_t)i * NB,
                in2f_WT + (size_t)(i + 1) * NB * NB,
                x_buf, xf_buf, N);
        } else {
            node_out_head_mfma<<<nblk_atom64, 256, 0, stream>>>(
                agg, oW1T + (size_t)i * NB * NB, f2out_b1 + (size_t)i * NB,
                oW2T + (size_t)i * NB * NB, f2out_b2 + (size_t)i * NB,
                x_buf, batch, hW1T, head_b1, head_W2,
                (float*)d_out, N);
        }
    }
}